// Round 6
// baseline (115.877 us; speedup 1.0000x reference)
//
#include <hip/hip_runtime.h>
#include <math.h>

typedef _Float16 half8  __attribute__((ext_vector_type(8)));
typedef _Float16 half4v __attribute__((ext_vector_type(4)));
typedef float    float4v __attribute__((ext_vector_type(4)));

#define BM   128
#define KDIM 256
#define CH   64          // k-chunk (floats)
#define NCH  4           // KDIM / CH
#define XBS  72          // per-wave x buffer row stride (halves): 64+8 pad
#define WSTR 264         // W1 LDS row stride (halves): 256+8 pad
#define HSW  65          // fp32 h-tile stride: (r+k)%32 -> 2-way (free)

__global__ __launch_bounds__(512, 4)
void qc_fused(const float* __restrict__ x,
              const float* __restrict__ W1,
              const float* __restrict__ b1,
              const float* __restrict__ W2,
              const float* __restrict__ b2,
              const float* __restrict__ qw,
              float* __restrict__ out)
{
    __shared__ _Float16 wh[64 * WSTR];          // 33792 B; overlaid by fp32 hs after GEMM1
    __shared__ _Float16 xb[8 * 2 * 16 * XBS];   // 36864 B: per-wave double-buffered x tiles
    __shared__ float ure[256], uim[256];        // U columns (16x16 complex)
    __shared__ __align__(16) float Asym[256];   // A = Re(U^dag Z0 U), real symmetric 16x16
    __shared__ float w2s[256];
    __shared__ float b1s[64];
    __shared__ float b2s[4];
    __shared__ float trig[32];                  // [layer][qubit][{cy,sy,cz,sz}]

    const int tid  = threadIdx.x;
    const int lane = tid & 63;
    const int wv   = tid >> 6;                  // wave 0..7 -> rows wv*16..wv*16+15
    const int m    = lane & 15;
    const int q    = lane >> 4;
    const int row0 = blockIdx.x * BM;

    // ---- one-time per-block setup (before the single stage barrier) ----
    if (tid < 256) w2s[tid] = W2[tid];
    if (tid < 64)  b1s[tid] = b1[tid];
    if (tid < 4)   b2s[tid] = b2[tid];
    if (tid < 8) {
        int l = tid >> 2, i = tid & 3;
        float wy = qw[(l * 4 + i) * 2 + 0];
        float wz = qw[(l * 4 + i) * 2 + 1];
        float sy, cy, sz, cz;
        sincosf(0.5f * wy, &sy, &cy);
        sincosf(0.5f * wz, &sz, &cz);
        trig[(l * 4 + i) * 4 + 0] = cy;
        trig[(l * 4 + i) * 4 + 1] = sy;
        trig[(l * 4 + i) * 4 + 2] = cz;
        trig[(l * 4 + i) * 4 + 3] = sz;
    }

    // ---- stage full W1 (fp32 -> fp16) once: thread t does row t>>3, 32-col eighth ----
    {
        const int wr = tid >> 3;
        const int c0 = (tid & 7) * 32;
        const float* wp = W1 + (size_t)wr * KDIM + c0;
        _Float16* dst = &wh[wr * WSTR + c0];
        #pragma unroll
        for (int j = 0; j < 8; ++j) {
            float4v v = *(const float4v*)(wp + 4 * j);
            half4v h;
            h[0] = (_Float16)v[0]; h[1] = (_Float16)v[1];
            h[2] = (_Float16)v[2]; h[3] = (_Float16)v[3];
            *(half4v*)(dst + 4 * j) = h;
        }
    }

    // ---- x staging geometry: per chunk a wave covers its 16 rows x 64 floats, coalesced ----
    const float* xw = x + (size_t)(row0 + wv * 16) * KDIM;   // this wave's 16 rows
    _Float16* xbw = &xb[wv * (2 * 16 * XBS)];                // this wave's private dbuf
    const int srow = lane >> 4;          // 0..3
    const int scol = (lane & 15) * 4;    // float col 0..60

    // prologue: issue chunk-0 AND chunk-1 loads (2-deep pipeline from the start)
    float4v xr[2][4];                    // [chunk parity][quad]; fully unrolled -> static idx
    #pragma unroll
    for (int t = 0; t < 4; ++t)
        xr[0][t] = *(const float4v*)(xw + (size_t)(4 * t + srow) * KDIM + 0 * CH + scol);
    #pragma unroll
    for (int t = 0; t < 4; ++t)
        xr[1][t] = *(const float4v*)(xw + (size_t)(4 * t + srow) * KDIM + 1 * CH + scol);

    __syncthreads();   // barrier #1: W1 + trig resident

    // write chunk 0 into buffer 0 (wave-private)
    #pragma unroll
    for (int t = 0; t < 4; ++t) {
        half4v h;
        h[0] = (_Float16)xr[0][t][0]; h[1] = (_Float16)xr[0][t][1];
        h[2] = (_Float16)xr[0][t][2]; h[3] = (_Float16)xr[0][t][3];
        *(half4v*)&xbw[(4 * t + srow) * XBS + scol] = h;
    }

    // ---- wave 7: evolve the fixed circuit unitary U and build A = Re(U^dag Z0 U).
    //      Hidden under the BW-bound GEMM phase of the other waves.
    if (wv == 7) {
        if (lane < 16) {
            float re[16], im[16];
            #pragma unroll
            for (int idx = 0; idx < 16; ++idx) {
                re[idx] = (idx == lane) ? 1.0f : 0.0f;
                im[idx] = 0.0f;
            }
            #pragma unroll
            for (int l = 0; l < 2; ++l) {
                #pragma unroll
                for (int i = 0; i < 4; ++i) {
                    const float cy = trig[(l * 4 + i) * 4 + 0];
                    const float sy = trig[(l * 4 + i) * 4 + 1];
                    const float cz = trig[(l * 4 + i) * 4 + 2];
                    const float sz = trig[(l * 4 + i) * 4 + 3];
                    const int mq = 8 >> i;
                    #pragma unroll
                    for (int idx = 0; idx < 16; ++idx) {
                        if (!(idx & mq)) {
                            int j = idx | mq;
                            float ar = re[idx], ai = im[idx], br = re[j], bi = im[j];
                            re[idx] = fmaf(cy, ar, -sy * br);
                            im[idx] = fmaf(cy, ai, -sy * bi);
                            re[j]   = fmaf(sy, ar,  cy * br);
                            im[j]   = fmaf(sy, ai,  cy * bi);
                        }
                    }
                    #pragma unroll
                    for (int idx = 0; idx < 16; ++idx) {
                        float sgn = (idx & mq) ? sz : -sz;
                        float ar = re[idx], ai = im[idx];
                        re[idx] = fmaf(ar, cz, -ai * sgn);
                        im[idx] = fmaf(ar, sgn, ai * cz);
                    }
                }
                #pragma unroll
                for (int c = 0; c < 4; ++c) {
                    int t  = (c + 1) & 3;
                    int mc = 8 >> c, mt = 8 >> t;
                    #pragma unroll
                    for (int idx = 0; idx < 16; ++idx) {
                        if ((idx & mc) && !(idx & mt)) {
                            int j = idx | mt;
                            float tr = re[idx]; re[idx] = re[j]; re[j] = tr;
                            float ti = im[idx]; im[idx] = im[j]; im[j] = ti;
                        }
                    }
                }
            }
            #pragma unroll
            for (int idx = 0; idx < 16; ++idx) {
                ure[idx * 16 + lane] = re[idx];
                uim[idx * 16 + lane] = im[idx];
            }
        }
        __threadfence_block();   // same-wave ds_write -> ds_read ordering
        // A[i][j] = sum_s z_s (Ur[s][i]Ur[s][j] + Ui[s][i]Ui[s][j]);  lane: i = lane&15, j = (lane>>4)*4+t
        const int ai = lane & 15;
        #pragma unroll
        for (int t = 0; t < 4; ++t) {
            const int aj = (lane >> 4) * 4 + t;
            float s = 0.0f;
            #pragma unroll
            for (int s16 = 0; s16 < 16; ++s16) {
                float term = fmaf(ure[s16 * 16 + ai], ure[s16 * 16 + aj],
                                  uim[s16 * 16 + ai] * uim[s16 * 16 + aj]);
                s += (s16 & 8) ? -term : term;
            }
            Asym[ai * 16 + aj] = s;
        }
    }

    // ---- GEMM1 main loop: per-wave dbuf, loads issued TWO chunks ahead, no block barriers ----
    float4v acc[4] = {};                 // 1 row-tile x 4 col-tiles
    #pragma unroll
    for (int c = 0; c < NCH; ++c) {
        // issue chunk c+2's loads into the reg set that held chunk c (already in LDS)
        if (c + 2 < NCH) {
            #pragma unroll
            for (int t = 0; t < 4; ++t)
                xr[c & 1][t] = *(const float4v*)(xw + (size_t)(4 * t + srow) * KDIM
                                                 + (c + 2) * CH + scol);
        }
        // compute chunk c from buffer c&1
        const _Float16* bufc = &xbw[(c & 1) * (16 * XBS)];
        #pragma unroll
        for (int ks = 0; ks < 2; ++ks) {
            const int ko = ks * 32 + q * 8;
            half8 af = *(const half8*)&bufc[m * XBS + ko];
            #pragma unroll
            for (int b = 0; b < 4; ++b) {
                half8 bf = *(const half8*)&wh[(16 * b + m) * WSTR + c * CH + ko];
                acc[b] = __builtin_amdgcn_mfma_f32_16x16x32_f16(af, bf, acc[b], 0, 0, 0);
            }
        }
        // convert + write chunk c+1 (loaded two iterations ago / in prologue) into its buffer
        if (c + 1 < NCH) {
            _Float16* nb = &xbw[((c + 1) & 1) * (16 * XBS)];
            #pragma unroll
            for (int t = 0; t < 4; ++t) {
                half4v h;
                h[0] = (_Float16)xr[(c + 1) & 1][t][0];
                h[1] = (_Float16)xr[(c + 1) & 1][t][1];
                h[2] = (_Float16)xr[(c + 1) & 1][t][2];
                h[3] = (_Float16)xr[(c + 1) & 1][t][3];
                *(half4v*)&nb[(4 * t + srow) * XBS + scol] = h;
            }
        }
    }

    __syncthreads();   // barrier #2: all waves done reading wh; wave-7 A done

    // ---- epilogue: bias + relu -> hs (fp32, overlaid on wh) ----
    float* hs = (float*)wh;
    #pragma unroll
    for (int b = 0; b < 4; ++b) {
        #pragma unroll
        for (int i = 0; i < 4; ++i) {
            int row = wv * 16 + 4 * q + i;    // C/D: row = quad*4+reg
            int col = 16 * b + m;             //      col = lane&15
            float v = acc[b][i] + b1s[col];
            hs[row * HSW + col] = fmaxf(v, 0.0f);
        }
    }
    __syncthreads();   // barrier #3

    // ---- GEMM2 + tanh + quadratic form: one thread per row ----
    if (tid < BM) {
        const int r = tid;
        float s0 = b2s[0], s1 = b2s[1], s2 = b2s[2], s3 = b2s[3];
        #pragma unroll 8
        for (int k = 0; k < 64; ++k) {
            float hv = hs[r * HSW + k];       // (r+k)%32 -> 2-way, free
            s0 = fmaf(hv, w2s[0 * 64 + k], s0);
            s1 = fmaf(hv, w2s[1 * 64 + k], s1);
            s2 = fmaf(hv, w2s[2 * 64 + k], s2);
            s3 = fmaf(hv, w2s[3 * 64 + k], s3);
        }
        float ang[4] = { tanhf(s0), tanhf(s1), tanhf(s2), tanhf(s3) };

        float ca[4], sa[4];
        #pragma unroll
        for (int i = 0; i < 4; ++i)
            __sincosf(0.5f * ang[i], &sa[i], &ca[i]);

        // v = product state amplitudes (real); idx = w0*8 + w1*4 + w2*2 + w3
        float v[16];
        #pragma unroll
        for (int idx = 0; idx < 16; ++idx) {
            v[idx] = (idx & 8 ? sa[0] : ca[0]) * (idx & 4 ? sa[1] : ca[1]) *
                     (idx & 2 ? sa[2] : ca[2]) * (idx & 1 ? sa[3] : ca[3]);
        }
        // z = v^T A v
        float z = 0.0f;
        #pragma unroll
        for (int i = 0; i < 16; ++i) {
            const float4v a0 = *(const float4v*)&Asym[i * 16 + 0];
            const float4v a1 = *(const float4v*)&Asym[i * 16 + 4];
            const float4v a2 = *(const float4v*)&Asym[i * 16 + 8];
            const float4v a3 = *(const float4v*)&Asym[i * 16 + 12];
            float w = 0.0f;
            w = fmaf(a0[0], v[0],  w); w = fmaf(a0[1], v[1],  w);
            w = fmaf(a0[2], v[2],  w); w = fmaf(a0[3], v[3],  w);
            w = fmaf(a1[0], v[4],  w); w = fmaf(a1[1], v[5],  w);
            w = fmaf(a1[2], v[6],  w); w = fmaf(a1[3], v[7],  w);
            w = fmaf(a2[0], v[8],  w); w = fmaf(a2[1], v[9],  w);
            w = fmaf(a2[2], v[10], w); w = fmaf(a2[3], v[11], w);
            w = fmaf(a3[0], v[12], w); w = fmaf(a3[1], v[13], w);
            w = fmaf(a3[2], v[14], w); w = fmaf(a3[3], v[15], w);
            z = fmaf(v[i], w, z);
        }
        out[row0 + r] = z;
    }
}

extern "C" void kernel_launch(void* const* d_in, const int* in_sizes, int n_in,
                              void* d_out, int out_size, void* d_ws, size_t ws_size,
                              hipStream_t stream) {
    const float* x  = (const float*)d_in[0];
    const float* W1 = (const float*)d_in[1];
    const float* b1 = (const float*)d_in[2];
    const float* W2 = (const float*)d_in[3];
    const float* b2 = (const float*)d_in[4];
    const float* qw = (const float*)d_in[5];
    float* out = (float*)d_out;
    const int B = in_sizes[0] / KDIM;   // 65536
    qc_fused<<<B / BM, 512, 0, stream>>>(x, W1, b1, W2, b2, qw, out);
}

// Round 7
// 104.017 us; speedup vs baseline: 1.1140x; 1.1140x over previous
//
#include <hip/hip_runtime.h>
#include <math.h>

typedef _Float16 half8  __attribute__((ext_vector_type(8)));
typedef _Float16 half4v __attribute__((ext_vector_type(4)));
typedef float    float4v __attribute__((ext_vector_type(4)));

#define BM   128
#define KDIM 256
#define BKF  128     // K-chunk (floats/halves)
#define XSTR 136     // halves per LDS row = BKF + 8 pad; 272 B, 16B-aligned
#define HSW  65      // fp32 h-tile stride: (r+k)%32 -> 2-way (free)

__global__ __launch_bounds__(256, 3)
void qc_fused(const float* __restrict__ x,
              const float* __restrict__ W1,
              const float* __restrict__ b1,
              const float* __restrict__ W2,
              const float* __restrict__ b2,
              const float* __restrict__ qw,
              float* __restrict__ out)
{
    __shared__ _Float16 xh[BM * XSTR];   // 34816 B; reused as fp32 hs[128*65] later
    __shared__ _Float16 wh[64 * XSTR];   // 17408 B
    __shared__ float w2s[256];
    __shared__ float b1s[64];
    __shared__ float b2s[4];
    __shared__ float trig[32];           // [layer][qubit][{cy,sy,cz,sz}]

    const int tid  = threadIdx.x;
    const int lane = tid & 63;
    const int wv   = tid >> 6;           // wave 0..3 -> rows wv*32..wv*32+31
    const int m    = lane & 15;
    const int q    = lane >> 4;
    const int row0 = blockIdx.x * BM;

    // ---- one-time per-block setup (before first sync) ----
    w2s[tid] = W2[tid];                  // 4*64 = 256
    if (tid < 64) b1s[tid] = b1[tid];
    if (tid < 4)  b2s[tid] = b2[tid];
    if (tid < 8) {
        int l = tid >> 2, i = tid & 3;
        float wy = qw[(l * 4 + i) * 2 + 0];
        float wz = qw[(l * 4 + i) * 2 + 1];
        float sy, cy, sz, cz;
        sincosf(0.5f * wy, &sy, &cy);
        sincosf(0.5f * wz, &sz, &cz);
        trig[(l * 4 + i) * 4 + 0] = cy;
        trig[(l * 4 + i) * 4 + 1] = sy;
        trig[(l * 4 + i) * 4 + 2] = cz;
        trig[(l * 4 + i) * 4 + 3] = sz;
    }

    float4v acc[2][4] = {};              // 2 row-tiles x 4 col-tiles, fp32

    const int sr  = tid >> 3, skq = tid & 7;   // x staging: 32 rows x 8 k-quads
    const int wr  = tid >> 2, wkq = tid & 3;   // W staging: 64 rows x 4 k-quads

    for (int kc = 0; kc < KDIM; kc += BKF) {
        if (kc) __syncthreads();
        // ---- stage x chunk: 128 rows x 128 k, fp32 -> fp16 ----
        #pragma unroll
        for (int i = 0; i < 4; ++i) {
            #pragma unroll
            for (int j = 0; j < 4; ++j) {
                int row = sr + 32 * i;
                int kf  = 4 * skq + 32 * j;
                const float4v v = *(const float4v*)(x + (size_t)(row0 + row) * KDIM + kc + kf);
                half4v h;
                h[0] = (_Float16)v[0]; h[1] = (_Float16)v[1];
                h[2] = (_Float16)v[2]; h[3] = (_Float16)v[3];
                *(half4v*)&xh[row * XSTR + kf] = h;
            }
        }
        // ---- stage W1 chunk: 64 rows x 128 k ----
        #pragma unroll
        for (int j = 0; j < 8; ++j) {
            int kf = 4 * wkq + 16 * j;
            const float4v v = *(const float4v*)(W1 + (size_t)wr * KDIM + kc + kf);
            half4v h;
            h[0] = (_Float16)v[0]; h[1] = (_Float16)v[1];
            h[2] = (_Float16)v[2]; h[3] = (_Float16)v[3];
            *(half4v*)&wh[wr * XSTR + kf] = h;
        }
        __syncthreads();
        // ---- MFMA inner loop: 4 k-steps of 32 ----
        #pragma unroll
        for (int ks = 0; ks < 4; ++ks) {
            const int ko = ks * 32 + q * 8;
            half8 af0 = *(const half8*)&xh[(wv * 32 +      m) * XSTR + ko];
            half8 af1 = *(const half8*)&xh[(wv * 32 + 16 + m) * XSTR + ko];
            #pragma unroll
            for (int b = 0; b < 4; ++b) {
                half8 bf = *(const half8*)&wh[(16 * b + m) * XSTR + ko];
                acc[0][b] = __builtin_amdgcn_mfma_f32_16x16x32_f16(af0, bf, acc[0][b], 0, 0, 0);
                acc[1][b] = __builtin_amdgcn_mfma_f32_16x16x32_f16(af1, bf, acc[1][b], 0, 0, 0);
            }
        }
    }
    __syncthreads();

    // ---- epilogue: bias + relu -> hs (fp32, reuse xh region) ----
    float* hs = (float*)xh;
    #pragma unroll
    for (int a = 0; a < 2; ++a) {
        #pragma unroll
        for (int b = 0; b < 4; ++b) {
            #pragma unroll
            for (int i = 0; i < 4; ++i) {
                int row = wv * 32 + 16 * a + 4 * q + i;   // C/D: row = quad*4+reg
                int col = 16 * b + m;                     //      col = lane&15
                float v = acc[a][b][i] + b1s[col];
                hs[row * HSW + col] = fmaxf(v, 0.0f);
            }
        }
    }
    __syncthreads();

    // ---- GEMM2 + tanh + quantum circuit: one thread per row ----
    if (tid < BM) {
        const int r = tid;
        float s0 = b2s[0], s1 = b2s[1], s2 = b2s[2], s3 = b2s[3];
        #pragma unroll 8
        for (int k = 0; k < 64; ++k) {
            float hv = hs[r * HSW + k];       // (r+k)%32 -> 2-way, free
            s0 = fmaf(hv, w2s[0 * 64 + k], s0);   // w2s broadcast, free
            s1 = fmaf(hv, w2s[1 * 64 + k], s1);
            s2 = fmaf(hv, w2s[2 * 64 + k], s2);
            s3 = fmaf(hv, w2s[3 * 64 + k], s3);
        }
        float ang[4] = { tanhf(s0), tanhf(s1), tanhf(s2), tanhf(s3) };

        float ca[4], sa[4];
        #pragma unroll
        for (int i = 0; i < 4; ++i)
            __sincosf(0.5f * ang[i], &sa[i], &ca[i]);

        // state idx = w0*8 + w1*4 + w2*2 + w3
        float re[16], im[16];
        #pragma unroll
        for (int idx = 0; idx < 16; ++idx) {
            re[idx] = (idx & 8 ? sa[0] : ca[0]) * (idx & 4 ? sa[1] : ca[1]) *
                      (idx & 2 ? sa[2] : ca[2]) * (idx & 1 ? sa[3] : ca[3]);
            im[idx] = 0.0f;
        }
        #pragma unroll
        for (int l = 0; l < 2; ++l) {
            #pragma unroll
            for (int i = 0; i < 4; ++i) {
                const float cy = trig[(l * 4 + i) * 4 + 0];
                const float sy = trig[(l * 4 + i) * 4 + 1];
                const float cz = trig[(l * 4 + i) * 4 + 2];
                const float sz = trig[(l * 4 + i) * 4 + 3];
                const int mq = 8 >> i;
                #pragma unroll
                for (int idx = 0; idx < 16; ++idx) {
                    if (!(idx & mq)) {
                        int j = idx | mq;
                        float ar = re[idx], ai = im[idx], br = re[j], bi = im[j];
                        re[idx] = fmaf(cy, ar, -sy * br);
                        im[idx] = fmaf(cy, ai, -sy * bi);
                        re[j]   = fmaf(sy, ar,  cy * br);
                        im[j]   = fmaf(sy, ai,  cy * bi);
                    }
                }
                #pragma unroll
                for (int idx = 0; idx < 16; ++idx) {
                    float sgn = (idx & mq) ? sz : -sz;
                    float ar = re[idx], ai = im[idx];
                    re[idx] = fmaf(ar, cz, -ai * sgn);
                    im[idx] = fmaf(ar, sgn, ai * cz);
                }
            }
            #pragma unroll
            for (int c = 0; c < 4; ++c) {
                int t  = (c + 1) & 3;
                int mc = 8 >> c, mt = 8 >> t;
                #pragma unroll
                for (int idx = 0; idx < 16; ++idx) {
                    if ((idx & mc) && !(idx & mt)) {
                        int j = idx | mt;
                        float tr = re[idx]; re[idx] = re[j]; re[j] = tr;
                        float ti = im[idx]; im[idx] = im[j]; im[j] = ti;
                    }
                }
            }
        }
        float z = 0.0f;
        #pragma unroll
        for (int idx = 0; idx < 16; ++idx) {
            float p = re[idx] * re[idx] + im[idx] * im[idx];
            z += (idx & 8) ? -p : p;
        }
        out[row0 + r] = z;
    }
}

extern "C" void kernel_launch(void* const* d_in, const int* in_sizes, int n_in,
                              void* d_out, int out_size, void* d_ws, size_t ws_size,
                              hipStream_t stream) {
    const float* x  = (const float*)d_in[0];
    const float* W1 = (const float*)d_in[1];
    const float* b1 = (const float*)d_in[2];
    const float* W2 = (const float*)d_in[3];
    const float* b2 = (const float*)d_in[4];
    const float* qw = (const float*)d_in[5];
    float* out = (float*)d_out;
    const int B = in_sizes[0] / KDIM;   // 65536
    qc_fused<<<B / BM, 256, 0, stream>>>(x, W1, b1, W2, b2, qw, out);
}